// Round 10
// baseline (251.398 us; speedup 1.0000x reference)
//
#include <hip/hip_runtime.h>
#include <math.h>

// FilterDetection: score threshold + morphological opening (erode 4x4,
// dilate 4x4) on 32x1024x1024 f32.
//
// Round-16 design: BARRIER-FREE per-wave-private LDS pipeline.
//   Round-9 post-mortem: the inline-asm register ring (rounds 14/15) core-
//   dumped twice (second time WITH early-clobber -> theory falsified);
//   abandoned per pre-commitment. Return to the verified round-13 LDS
//   design (87.5us, passed) and remove its two measured costs:
//     (a) 22 s_barriers/block convoying 4 waves -- existed ONLY because
//         waves read seam columns staged by the neighbor wave. Fix: each
//         wave stages its OWN halo into a PRIVATE region
//         [4L | 4R | 256 own] (264 floats) per ring slot. No cross-wave
//         deps -> zero barriers; producer==consumer wave -> counted
//         s_waitcnt vmcnt(K) alone orders staging vs ds_read.
//     (b) SQ_LDS_BANK_CONFLICT 1.08e7 (~20% of runtime): de-synchronized
//         waves + per-wave regions offset by 8 banks (1056B stride)
//         soften the post-barrier burst alias pattern (full fix, if
//         needed, is shfl-consume next round).
//   LDS: 4 slots x 4 waves x 264 floats = 16896 B (same as round 13).
//   Stage per wave per row: 2 x global_load_lds width=16 (own 1KB all
//   lanes; halo 32B lanes 0/1 with per-lane clamped sources). vmcnt
//   ledger at STEP(IT): K = 2*[IT+1<22] + 2*[IT+2<22] + [IT>=7] + [IT>=8]
//   (stores are single pinned global_store_dwordx4 ops; miscount can only
//   over-wait). sched_barrier(0) after each wait (rule #18).
//   Consume: 3 aligned ds_read_b128 from the private region; per-lane
//   byte offsets a0=(l==0?0:16+16l), a1=32+16l, a2=(l==63?16:48+16l).
//
// Kept: one block = one (img,strip) with 4 waves = 4 x 256-col segments;
// XCD-chunked bijective swizzle; two-level sliding min/max pipelines;
// row-clamped staging + uniform OOB fold; image-edge +inf via eL/eR
// selects (monotone threshold deferred to store; absmax=0 rounds 1-13);
// score blocks first; plain coherent stores.
//
// Window geometry (from lax.reduce_window padding):
//   erode : offsets [-2..+1] both axes, OOB = +inf
//   dilate: offsets [-1..+2] both axes, OOB = -inf
// Per lane (4 out cols c0..c0+3): raw c0-3..c0+6, eroded c0-1..c0+5.

#define H 1024
#define W 1024
#define R 16
#define STRIPS (H / R)                    // 64
#define BATCH 32
#define MASK_BLOCKS (STRIPS * BATCH)      // 2048 blocks: one per (img,strip)
#define N_SCORE 32000
#define SCORE_BLOCKS ((N_SCORE + 255) / 256)  // 125
#define ITERS (R + 6)                     // 22 raw rows per strip
#define REGF 264                          // floats per (slot,wave) region
#define NSLOT 4

__device__ __forceinline__ float th(float v) { return v >= 0.5f ? v : 0.0f; }

__global__ __launch_bounds__(256)
void fused_kernel(const float* __restrict__ score,
                  const float* __restrict__ mask,
                  float* __restrict__ out) {
    const int bid0 = blockIdx.x;
    const int tid  = threadIdx.x;

    if (bid0 < SCORE_BLOCKS) {              // score threshold, dispatched first
        int i = bid0 * 256 + tid;
        if (i < N_SCORE) out[i] = th(score[i]);
        return;
    }
    const int mb0 = bid0 - SCORE_BLOCKS;
    // XCD swizzle: contiguous 256-block chunk per XCD -> adjacent strips'
    // 6 shared halo rows hit the same XCD L2.
    const int bid = (mb0 & 7) * (MASK_BLOCKS / 8) + (mb0 >> 3);

    const int b     = bid >> 6;             // image
    const int strip = bid & 63;
    const int y0    = strip * R;
    const int wave  = tid >> 6;
    const int lane  = tid & 63;
    const int c0w   = wave << 8;            // wave's first col (256-col segment)
    const int c0    = c0w + (lane << 2);    // this lane's 4 output cols

    const float* img  = mask + (size_t)b * (H * W);
    float*       outp = out + N_SCORE + (size_t)b * (H * W);

    __shared__ float smem[NSLOT * 4 * REGF];   // 16896 B

    const bool eL = (c0 == 0);              // image-left lane
    const bool eR = (c0 == W - 4);          // image-right lane
    // Halo-stage source col (per-lane; lanes>=2 unused but in-bounds):
    //   lane 0 -> left 16B (cols c0w-4..c0w-1, clamped at image edge)
    //   lane 1 -> right 16B (cols c0w+256..+259, clamped at image edge)
    const int oH = (lane == 0) ? (c0w > 0 ? c0w - 4 : 0)
                               : (c0w + 256 < W ? c0w + 256 : W - 4);
    // Consume byte offsets within the region (per-lane constants):
    const int a0 = (lane == 0)  ? 0  : (16 + (lane << 4));
    const int a1 = 32 + (lane << 4);
    const int a2 = (lane == 63) ? 16 : (48 + (lane << 4));

    // ---- stage raw row (y0-3+IT), clamped, into this wave's region ----
#define STAGE(IT) do {                                                        \
        int t_  = y0 - 3 + (IT);                                              \
        int tc_ = t_ < 0 ? 0 : (t_ > H - 1 ? H - 1 : t_);  /* uniform */      \
        const float* row_ = img + (size_t)tc_ * W;                            \
        float* rg_ = &smem[((((IT) & 3) << 2) + wave) * REGF];                \
        __builtin_amdgcn_global_load_lds(                                     \
            (const __attribute__((address_space(1))) void*)(row_ + c0w + (lane << 2)), \
            (__attribute__((address_space(3))) void*)(rg_ + 8), 16, 0, 0);    \
        if (lane < 2) {                                                       \
            __builtin_amdgcn_global_load_lds(                                 \
                (const __attribute__((address_space(1))) void*)(row_ + oH),   \
                (__attribute__((address_space(3))) void*)(rg_), 16, 0, 0);    \
        }                                                                     \
    } while (0)

    // Vertical-min pipeline over hmin rows (window t-3..t), 7 eroded cols:
    float hmP[7], q1[7], q2[7];
    for (int m = 0; m < 7; ++m) { hmP[m] = q1[m] = q2[m] = INFINITY; }
    // Vertical-max pipeline over hmax rows (window r-3..r), 4 out cols:
    float hxP[4], u1[4], u2[4];
    for (int j = 0; j < 4; ++j)  { hxP[j] = u1[j] = u2[j] = -INFINITY; }

    STAGE(0); STAGE(1);                     // prologue: depth-2 pipeline

    // Per step: stage row IT+2 (slot (IT+2)&3), wait for row IT's 2 stage
    // ops (counted vmcnt, never 0 mid-loop), consume from private region,
    // compute, store output row IT-6 (for IT>=6). No barriers anywhere.
#define STEP(IT) do {                                                         \
        if ((IT) + 2 < ITERS) STAGE((IT) + 2);                                \
        { constexpr int K_ = 2 * ((((IT)+1) < ITERS ? 1 : 0)                  \
                                + (((IT)+2) < ITERS ? 1 : 0))                 \
                           + ((IT) >= 7 ? 1 : 0) + ((IT) >= 8 ? 1 : 0);       \
          asm volatile("s_waitcnt vmcnt(%0)" :: "i"(K_) : "memory"); }        \
        __builtin_amdgcn_sched_barrier(0);                                    \
        {                                                                     \
            const int t = y0 - 3 + (IT);                                      \
            const bool rowOK = (t >= 0) && (t < H);        /* uniform */      \
            const char* rgc = (const char*)&smem[((((IT) & 3) << 2) + wave) * REGF]; \
            float4 A0 = *(const float4*)(rgc + a0);  /* cols c0-4..c0-1 */    \
            float4 A1 = *(const float4*)(rgc + a1);  /* cols c0  ..c0+3 */    \
            float4 A2 = *(const float4*)(rgc + a2);  /* cols c0+4..c0+7 */    \
            float ar[10];                                                     \
            ar[0] = eL ? INFINITY : A0.y;    /* col c0-3 */                   \
            ar[1] = eL ? INFINITY : A0.z;    /* col c0-2 */                   \
            ar[2] = eL ? INFINITY : A0.w;    /* col c0-1 */                   \
            ar[3] = A1.x; ar[4] = A1.y; ar[5] = A1.z; ar[6] = A1.w;           \
            ar[7] = eR ? INFINITY : A2.x;    /* col c0+4 */                   \
            ar[8] = eR ? INFINITY : A2.y;    /* col c0+5 */                   \
            ar[9] = eR ? INFINITY : A2.z;    /* col c0+6 */                   \
            float p[9];                                                       \
            for (int m = 0; m < 9; ++m) p[m] = fminf(ar[m], ar[m + 1]);       \
            float hm[7];                                                      \
            for (int m = 0; m < 7; ++m) {                                     \
                float v = fminf(p[m], p[m + 2]);                              \
                hm[m] = rowOK ? v : INFINITY;   /* erosion row pad */         \
            }                                                                 \
            const int r = t - 1;                                              \
            const float rlim = (r >= 0 && r < H) ? INFINITY : -INFINITY;      \
            float qt[7], ec[7];                                               \
            for (int m = 0; m < 7; ++m) {                                     \
                qt[m] = fminf(hmP[m], hm[m]);                                 \
                ec[m] = fminf(fminf(qt[m], q2[m]), rlim);                     \
            }                                                                 \
            ec[0] = eL ? -INFINITY : ec[0];     /* eroded col -1   */         \
            ec[5] = eR ? -INFINITY : ec[5];     /* eroded col 1024 */         \
            ec[6] = eR ? -INFINITY : ec[6];     /* eroded col 1025 */         \
            for (int m = 0; m < 7; ++m) { q2[m] = q1[m]; q1[m] = qt[m]; hmP[m] = hm[m]; } \
            float p2[6];                                                      \
            for (int j = 0; j < 6; ++j) p2[j] = fmaxf(ec[j], ec[j + 1]);      \
            float hx[4], ur[4];                                               \
            for (int j = 0; j < 4; ++j) {                                     \
                hx[j] = fmaxf(p2[j], p2[j + 2]);                              \
                ur[j] = fmaxf(hxP[j], hx[j]);                                 \
            }                                                                 \
            if ((IT) >= 6) {                                                  \
                const int y = t - 3;                                          \
                float o0 = th(fmaxf(ur[0], u2[0]));                           \
                float o1 = th(fmaxf(ur[1], u2[1]));                           \
                float o2 = th(fmaxf(ur[2], u2[2]));                           \
                float o3 = th(fmaxf(ur[3], u2[3]));                           \
                *(float4*)(outp + (size_t)y * W + c0) =                       \
                    make_float4(o0, o1, o2, o3);                              \
            }                                                                 \
            for (int j = 0; j < 4; ++j) { u2[j] = u1[j]; u1[j] = ur[j]; hxP[j] = hx[j]; } \
        }                                                                     \
    } while (0)

    STEP(0);  STEP(1);  STEP(2);  STEP(3);  STEP(4);  STEP(5);
    STEP(6);  STEP(7);  STEP(8);  STEP(9);  STEP(10); STEP(11);
    STEP(12); STEP(13); STEP(14); STEP(15); STEP(16); STEP(17);
    STEP(18); STEP(19); STEP(20); STEP(21);

#undef STEP
#undef STAGE
}

extern "C" void kernel_launch(void* const* d_in, const int* in_sizes, int n_in,
                              void* d_out, int out_size, void* d_ws, size_t ws_size,
                              hipStream_t stream) {
    const float* score = (const float*)d_in[0];
    const float* mask  = (const float*)d_in[1];
    float* out = (float*)d_out;

    const int grid = MASK_BLOCKS + SCORE_BLOCKS;
    fused_kernel<<<grid, 256, 0, stream>>>(score, mask, out);
}